// Round 4
// baseline (419.662 us; speedup 1.0000x reference)
//
#include <hip/hip_runtime.h>

#define S_LEN 2048
#define D_DIM 128
#define BM 128
#define BN 64
#define CHUNK 8            // KV tiles per chunk-block
#define NQT (S_LEN / BM)   // 16
#define TC_TOTAL 40        // sum over qt of ceil((2qt+2)/CHUNK)
#define SLOT 16640         // floats per partial slot: 128*128 O + 128 m + 128 l

typedef __attribute__((ext_vector_type(8))) short short8;
typedef __attribute__((ext_vector_type(4))) float floatx4;
typedef unsigned short u16;

__device__ __forceinline__ u16 f2b(float f) {
    union { float f; unsigned u; } x; x.f = f;
    unsigned r = x.u + 0x7FFFu + ((x.u >> 16) & 1u);  // RNE
    return (u16)(r >> 16);
}
__device__ __forceinline__ float b2f(u16 h) {
    union { unsigned u; float f; } x; x.u = ((unsigned)h) << 16;
    return x.f;
}
__device__ __forceinline__ void gld_lds16(const void* g, void* l) {
    __builtin_amdgcn_global_load_lds(
        (const __attribute__((address_space(1))) unsigned int*)g,
        (__attribute__((address_space(3))) unsigned int*)l, 16, 0, 0);
}
__device__ __forceinline__ floatx4 mfma16(short8 a, short8 b, floatx4 c) {
    return __builtin_amdgcn_mfma_f32_16x16x32_bf16(a, b, c, 0, 0, 0);
}

// ---------------- pre-pass: fp32 -> bf16 row-major (used for Q and K) ----------------
__global__ __launch_bounds__(256) void conv_bf16(const float* __restrict__ src,
                                                 u16* __restrict__ dst) {
    int idx = (blockIdx.x * 256 + threadIdx.x) * 4;
    float4 x = *(const float4*)(src + idx);
    ushort4 h;
    h.x = f2b(x.x); h.y = f2b(x.y); h.z = f2b(x.z); h.w = f2b(x.w);
    *(ushort4*)(dst + idx) = h;
}

// ---------------- pre-pass: V fp32 [bh][s][d] -> bf16 [bh][d][s] ----------------
// LDS fp32 tile 64s x 64d, row stride 65 dwords:
//   phase1 store bank = (s + 4b + e) mod 32  -> uniform 2-way (free)
//   phase2 read  bank = (4b + r + d) mod 32  -> uniform 2-way (free)
__global__ __launch_bounds__(256) void trans_v(const float* __restrict__ v,
                                               u16* __restrict__ vt) {
    __shared__ float T[64][65];
    const int s0  = (blockIdx.x >> 1) * 64;
    const int d0  = (blockIdx.x & 1) * 64;
    const int bh  = blockIdx.y;
    const int tid = threadIdx.x;
    const float* vb = v + ((size_t)bh * S_LEN + s0) * D_DIM + d0;
    #pragma unroll
    for (int i = 0; i < 4; ++i) {
        int unit = i * 256 + tid;        // 0..1023
        int s = unit >> 4;               // 0..63
        int c = (unit & 15) * 4;         // 0..60
        float4 x = *(const float4*)(vb + s * D_DIM + c);
        T[s][c + 0] = x.x; T[s][c + 1] = x.y;
        T[s][c + 2] = x.z; T[s][c + 3] = x.w;
    }
    __syncthreads();
    u16* ob = vt + (size_t)bh * D_DIM * S_LEN + (size_t)d0 * S_LEN + s0;
    #pragma unroll
    for (int i = 0; i < 4; ++i) {
        int unit = i * 256 + tid;   // 0..1023
        int d  = unit >> 4;         // 0..63
        int sl = (unit & 15) * 4;   // 0..60
        ushort4 h;
        h.x = f2b(T[sl + 0][d]); h.y = f2b(T[sl + 1][d]);
        h.z = f2b(T[sl + 2][d]); h.w = f2b(T[sl + 3][d]);
        *(ushort4*)(ob + (size_t)d * S_LEN + sl) = h;
    }
}

// ---------------- main: one (bh, q-tile, kv-chunk) per block ----------------
__global__ __launch_bounds__(256, 3) void fa_chunk(const u16* __restrict__ qw,
                                                   const u16* __restrict__ kw,
                                                   const u16* __restrict__ vtw,
                                                   float* __restrict__ parts) {
    __shared__ u16 Ks[BN * D_DIM];   // XOR-swizzled granules
    __shared__ u16 Vt[D_DIM * BN];   // XOR-swizzled granules
    __shared__ u16 Ps[4][32][72];

    // map blockIdx.x -> (qt, chunk)
    int bx = blockIdx.x, qt = 0, ch = bx;
    #pragma unroll 1
    for (int i = 0; i < NQT; ++i) {
        int cn = (2 * i + 2 + CHUNK - 1) / CHUNK;
        if (ch < cn) { qt = i; break; }
        ch -= cn;
    }
    const int bh   = blockIdx.y;
    const int q0   = qt * BM;
    const int tid  = threadIdx.x;
    const int w    = tid >> 6;
    const int lane = tid & 63;
    const int ln   = lane & 15;
    const int quad = lane >> 4;
    constexpr float QS = 0.08838834764831845f * 1.44269504088896340f;

    const int rowb0 = q0 + w * 16;
    const int NT = 2 * qt + 2;
    const int t0 = ch * CHUNK;
    const int t1 = (t0 + CHUNK < NT) ? t0 + CHUNK : NT;

    // ---- Q fragments: direct bf16 b128 loads (A-layout) ----
    short8 qf[2][4];
    #pragma unroll
    for (int m = 0; m < 2; ++m) {
        const u16* qrow = qw + ((size_t)bh * S_LEN + rowb0 + m * 64 + ln) * D_DIM;
        #pragma unroll
        for (int kc = 0; kc < 4; ++kc)
            qf[m][kc] = *(const short8*)(qrow + kc * 32 + quad * 8);
    }

    floatx4 o[2][8];
    #pragma unroll
    for (int m = 0; m < 2; ++m)
        #pragma unroll
        for (int db = 0; db < 8; ++db) o[m][db] = (floatx4){0.f, 0.f, 0.f, 0.f};
    float m_i[2][4], l_i[2][4];
    #pragma unroll
    for (int m = 0; m < 2; ++m)
        #pragma unroll
        for (int r = 0; r < 4; ++r) { m_i[m][r] = -1e30f; l_i[m][r] = 0.f; }

    const u16* kb_bh = kw + (size_t)bh * S_LEN * D_DIM;
    const u16* vb_bh = vtw + (size_t)bh * D_DIM * S_LEN;

    for (int t = t0; t < t1; ++t) {
        const int n0 = t * BN;
        {
            const u16* kb = kb_bh + (size_t)n0 * D_DIM;
            #pragma unroll
            for (int i = 0; i < 4; ++i) {
                int R0 = w * 16 + i * 4;
                int r = R0 + (lane >> 4);
                int p = lane & 15;
                gld_lds16(kb + r * D_DIM + ((p ^ (r & 7)) << 3), &Ks[R0 * D_DIM]);
            }
            #pragma unroll
            for (int i = 0; i < 4; ++i) {
                int D0 = (w * 4 + i) * 8;
                int d = D0 + (lane >> 3);
                int p = lane & 7;
                gld_lds16(vb_bh + (size_t)d * S_LEN + n0 + ((p ^ (d & 7)) << 3),
                          &Vt[D0 * BN]);
            }
        }
        __syncthreads();

        const bool skip0 = (n0 > rowb0 + 15);

        floatx4 sc[2][4];
        #pragma unroll
        for (int nb = 0; nb < 4; ++nb) {
            short8 kf[4];
            #pragma unroll
            for (int kc = 0; kc < 4; ++kc) {
                int r = nb * 16 + ln;
                kf[kc] = *(const short8*)&Ks[r * D_DIM + (((kc * 4 + quad) ^ (r & 7)) << 3)];
            }
            floatx4 a0 = (floatx4){0.f, 0.f, 0.f, 0.f};
            floatx4 a1 = (floatx4){0.f, 0.f, 0.f, 0.f};
            #pragma unroll
            for (int kc = 0; kc < 4; ++kc) {
                if (!skip0) a0 = mfma16(qf[0][kc], kf[kc], a0);
                a1 = mfma16(qf[1][kc], kf[kc], a1);
            }
            sc[0][nb] = a0; sc[1][nb] = a1;
        }

        #pragma unroll
        for (int m = 0; m < 2; ++m) {
            if (m == 0 && skip0) continue;
            const int rowb = rowb0 + m * 64;
            if (n0 + 63 > rowb) {
                #pragma unroll
                for (int nb = 0; nb < 4; ++nb) {
                    int colg = n0 + nb * 16 + ln;
                    #pragma unroll
                    for (int r = 0; r < 4; ++r)
                        if (colg > rowb + quad * 4 + r) sc[m][nb][r] = -1e30f;
                }
            }
            float mx[4];
            #pragma unroll
            for (int r = 0; r < 4; ++r)
                mx[r] = fmaxf(fmaxf(sc[m][0][r], sc[m][1][r]),
                              fmaxf(sc[m][2][r], sc[m][3][r]));
            #pragma unroll
            for (int off = 1; off < 16; off <<= 1) {
                #pragma unroll
                for (int r = 0; r < 4; ++r)
                    mx[r] = fmaxf(mx[r], __shfl_xor(mx[r], off));
            }
            float al[4], rs[4], mqs[4];
            #pragma unroll
            for (int r = 0; r < 4; ++r) {
                float mn = fmaxf(m_i[m][r], mx[r]);
                al[r] = __builtin_amdgcn_exp2f((m_i[m][r] - mn) * QS);
                m_i[m][r] = mn;
                mqs[r] = mn * QS;
                rs[r] = 0.f;
            }
            #pragma unroll
            for (int nb = 0; nb < 4; ++nb) {
                #pragma unroll
                for (int r = 0; r < 4; ++r) {
                    float p = __builtin_amdgcn_exp2f(fmaf(sc[m][nb][r], QS, -mqs[r]));
                    u16 hb = f2b(p);
                    Ps[w][m * 16 + quad * 4 + r][nb * 16 + ln] = hb;
                    rs[r] += b2f(hb);
                }
            }
            #pragma unroll
            for (int off = 1; off < 16; off <<= 1) {
                #pragma unroll
                for (int r = 0; r < 4; ++r) rs[r] += __shfl_xor(rs[r], off);
            }
            #pragma unroll
            for (int r = 0; r < 4; ++r) l_i[m][r] = l_i[m][r] * al[r] + rs[r];
            #pragma unroll
            for (int db = 0; db < 8; ++db) {
                #pragma unroll
                for (int r = 0; r < 4; ++r) o[m][db][r] *= al[r];
            }
        }

        short8 pf[2][2];
        #pragma unroll
        for (int m = 0; m < 2; ++m) {
            if (m == 0 && skip0) continue;
            #pragma unroll
            for (int kc = 0; kc < 2; ++kc)
                pf[m][kc] = *(const short8*)&Ps[w][m * 16 + ln][kc * 32 + quad * 8];
        }
        #pragma unroll
        for (int db = 0; db < 8; ++db) {
            short8 vf[2];
            #pragma unroll
            for (int kc = 0; kc < 2; ++kc) {
                int d = db * 16 + ln;
                vf[kc] = *(const short8*)&Vt[d * BN + (((kc * 4 + quad) ^ (d & 7)) << 3)];
            }
            if (!skip0) {
                o[0][db] = mfma16(pf[0][0], vf[0], o[0][db]);
                o[0][db] = mfma16(pf[0][1], vf[1], o[0][db]);
            }
            o[1][db] = mfma16(pf[1][0], vf[0], o[1][db]);
            o[1][db] = mfma16(pf[1][1], vf[1], o[1][db]);
        }
        __syncthreads();
    }

    // ---- epilogue: unnormalized partial (O, m*QS, l) ----
    float* slot = parts + ((size_t)bh * TC_TOTAL + blockIdx.x) * SLOT;
    #pragma unroll
    for (int m = 0; m < 2; ++m) {
        #pragma unroll
        for (int r = 0; r < 4; ++r) {
            int lrow = w * 16 + m * 64 + quad * 4 + r;
            float* orow = slot + lrow * D_DIM;
            #pragma unroll
            for (int db = 0; db < 8; ++db) orow[db * 16 + ln] = o[m][db][r];
            if (ln == 0) {
                slot[16384 + lrow] = m_i[m][r] * QS;
                slot[16512 + lrow] = l_i[m][r];
            }
        }
    }
}

// ---------------- combine partials per (bh, qt) ----------------
__global__ __launch_bounds__(256) void fa_combine(const float* __restrict__ parts,
                                                  float* __restrict__ out) {
    const int qt = blockIdx.x, bh = blockIdx.y;
    int pre = 0;
    #pragma unroll 1
    for (int i = 0; i < qt; ++i) pre += (2 * i + 2 + CHUNK - 1) / CHUNK;
    const int cn = (2 * qt + 2 + CHUNK - 1) / CHUNK;
    const float* base = parts + ((size_t)bh * TC_TOTAL + pre) * SLOT;
    const int c4 = (threadIdx.x & 31) * 4;
    const int rw = threadIdx.x >> 5;
    #pragma unroll 1
    for (int rp = 0; rp < 16; ++rp) {
        const int lrow = rp * 8 + rw;
        float M = -3.0e38f;
        for (int c = 0; c < cn; ++c)
            M = fmaxf(M, base[c * SLOT + 16384 + lrow]);
        float L = 0.f;
        float4 acc = {0.f, 0.f, 0.f, 0.f};
        for (int c = 0; c < cn; ++c) {
            const float* s = base + c * SLOT;
            float wc = exp2f(s[16384 + lrow] - M);
            L += s[16512 + lrow] * wc;
            float4 x = *(const float4*)(s + lrow * D_DIM + c4);
            acc.x += wc * x.x; acc.y += wc * x.y;
            acc.z += wc * x.z; acc.w += wc * x.w;
        }
        float inv = 1.f / L;
        float4 rr = {acc.x * inv, acc.y * inv, acc.z * inv, acc.w * inv};
        *(float4*)(out + ((size_t)bh * S_LEN + qt * BM + lrow) * D_DIM + c4) = rr;
    }
}

// ---------------- fallback: r2 monolithic kernel (fp32 q) ----------------
__global__ __launch_bounds__(256, 2) void fa_mono(const float* __restrict__ q,
                                                  const u16* __restrict__ kw,
                                                  const u16* __restrict__ vtw,
                                                  float* __restrict__ out) {
    __shared__ u16 Ks[BN * D_DIM];
    __shared__ u16 Vt[D_DIM * BN];
    __shared__ u16 Ps[4][32][72];

    const int qt   = blockIdx.x;
    const int bh   = blockIdx.y;
    const int q0   = qt * BM;
    const int tid  = threadIdx.x;
    const int w    = tid >> 6;
    const int lane = tid & 63;
    const int ln   = lane & 15;
    const int quad = lane >> 4;
    constexpr float qs = 0.08838834764831845f * 1.44269504088896340f;
    const int rowb0 = q0 + w * 16;

    short8 qf[2][4];
    #pragma unroll
    for (int m = 0; m < 2; ++m) {
        const float* qrow = q + ((size_t)bh * S_LEN + rowb0 + m * 64 + ln) * D_DIM;
        #pragma unroll
        for (int kc = 0; kc < 4; ++kc) {
            const float* p = qrow + kc * 32 + quad * 8;
            float4 x0 = *(const float4*)(p);
            float4 x1 = *(const float4*)(p + 4);
            short8 f;
            f[0] = (short)f2b(x0.x * qs); f[1] = (short)f2b(x0.y * qs);
            f[2] = (short)f2b(x0.z * qs); f[3] = (short)f2b(x0.w * qs);
            f[4] = (short)f2b(x1.x * qs); f[5] = (short)f2b(x1.y * qs);
            f[6] = (short)f2b(x1.z * qs); f[7] = (short)f2b(x1.w * qs);
            qf[m][kc] = f;
        }
    }
    floatx4 o[2][8];
    #pragma unroll
    for (int m = 0; m < 2; ++m)
        #pragma unroll
        for (int db = 0; db < 8; ++db) o[m][db] = (floatx4){0.f, 0.f, 0.f, 0.f};
    float m_i[2][4], l_i[2][4];
    #pragma unroll
    for (int m = 0; m < 2; ++m)
        #pragma unroll
        for (int r = 0; r < 4; ++r) { m_i[m][r] = -1e30f; l_i[m][r] = 0.f; }

    const u16* kb_bh = kw + (size_t)bh * S_LEN * D_DIM;
    const u16* vb_bh = vtw + (size_t)bh * D_DIM * S_LEN;

    const int NT = 2 * qt + 2;
    for (int t = 0; t < NT; ++t) {
        const int n0 = t * BN;
        {
            const u16* kb = kb_bh + (size_t)n0 * D_DIM;
            #pragma unroll
            for (int i = 0; i < 4; ++i) {
                int R0 = w * 16 + i * 4;
                int r = R0 + (lane >> 4);
                int p = lane & 15;
                gld_lds16(kb + r * D_DIM + ((p ^ (r & 7)) << 3), &Ks[R0 * D_DIM]);
            }
            #pragma unroll
            for (int i = 0; i < 4; ++i) {
                int D0 = (w * 4 + i) * 8;
                int d = D0 + (lane >> 3);
                int p = lane & 7;
                gld_lds16(vb_bh + (size_t)d * S_LEN + n0 + ((p ^ (d & 7)) << 3),
                          &Vt[D0 * BN]);
            }
        }
        __syncthreads();
        const bool skip0 = (n0 > rowb0 + 15);
        floatx4 sc[2][4];
        #pragma unroll
        for (int nb = 0; nb < 4; ++nb) {
            short8 kf[4];
            #pragma unroll
            for (int kc = 0; kc < 4; ++kc) {
                int r = nb * 16 + ln;
                kf[kc] = *(const short8*)&Ks[r * D_DIM + (((kc * 4 + quad) ^ (r & 7)) << 3)];
            }
            floatx4 a0 = (floatx4){0.f, 0.f, 0.f, 0.f};
            floatx4 a1 = (floatx4){0.f, 0.f, 0.f, 0.f};
            #pragma unroll
            for (int kc = 0; kc < 4; ++kc) {
                if (!skip0) a0 = mfma16(qf[0][kc], kf[kc], a0);
                a1 = mfma16(qf[1][kc], kf[kc], a1);
            }
            sc[0][nb] = a0; sc[1][nb] = a1;
        }
        #pragma unroll
        for (int m = 0; m < 2; ++m) {
            if (m == 0 && skip0) continue;
            const int rowb = rowb0 + m * 64;
            if (n0 + 63 > rowb) {
                #pragma unroll
                for (int nb = 0; nb < 4; ++nb) {
                    int colg = n0 + nb * 16 + ln;
                    #pragma unroll
                    for (int r = 0; r < 4; ++r)
                        if (colg > rowb + quad * 4 + r) sc[m][nb][r] = -1e30f;
                }
            }
            float mx[4];
            #pragma unroll
            for (int r = 0; r < 4; ++r)
                mx[r] = fmaxf(fmaxf(sc[m][0][r], sc[m][1][r]),
                              fmaxf(sc[m][2][r], sc[m][3][r]));
            #pragma unroll
            for (int off = 1; off < 16; off <<= 1) {
                #pragma unroll
                for (int r = 0; r < 4; ++r)
                    mx[r] = fmaxf(mx[r], __shfl_xor(mx[r], off));
            }
            float al[4], rs[4];
            #pragma unroll
            for (int r = 0; r < 4; ++r) {
                float mn = fmaxf(m_i[m][r], mx[r]);
                al[r] = __builtin_amdgcn_exp2f(m_i[m][r] - mn);
                m_i[m][r] = mn;
                rs[r] = 0.f;
            }
            #pragma unroll
            for (int nb = 0; nb < 4; ++nb) {
                #pragma unroll
                for (int r = 0; r < 4; ++r) {
                    float p = __builtin_amdgcn_exp2f(sc[m][nb][r] - m_i[m][r]);
                    u16 hb = f2b(p);
                    Ps[w][m * 16 + quad * 4 + r][nb * 16 + ln] = hb;
                    rs[r] += b2f(hb);
                }
            }
            #pragma unroll
            for (int off = 1; off < 16; off <<= 1) {
                #pragma unroll
                for (int r = 0; r < 4; ++r) rs[r] += __shfl_xor(rs[r], off);
            }
            #pragma unroll
            for (int r = 0; r < 4; ++r) l_i[m][r] = l_i[m][r] * al[r] + rs[r];
            #pragma unroll
            for (int db = 0; db < 8; ++db) {
                #pragma unroll
                for (int r = 0; r < 4; ++r) o[m][db][r] *= al[r];
            }
        }
        short8 pf[2][2];
        #pragma unroll
        for (int m = 0; m < 2; ++m) {
            if (m == 0 && skip0) continue;
            #pragma unroll
            for (int kc = 0; kc < 2; ++kc)
                pf[m][kc] = *(const short8*)&Ps[w][m * 16 + ln][kc * 32 + quad * 8];
        }
        #pragma unroll
        for (int db = 0; db < 8; ++db) {
            short8 vf[2];
            #pragma unroll
            for (int kc = 0; kc < 2; ++kc) {
                int d = db * 16 + ln;
                vf[kc] = *(const short8*)&Vt[d * BN + (((kc * 4 + quad) ^ (d & 7)) << 3)];
            }
            if (!skip0) {
                o[0][db] = mfma16(pf[0][0], vf[0], o[0][db]);
                o[0][db] = mfma16(pf[0][1], vf[1], o[0][db]);
            }
            o[1][db] = mfma16(pf[1][0], vf[0], o[1][db]);
            o[1][db] = mfma16(pf[1][1], vf[1], o[1][db]);
        }
        __syncthreads();
    }
    #pragma unroll
    for (int m = 0; m < 2; ++m) {
        #pragma unroll
        for (int r = 0; r < 4; ++r) {
            float inv = 1.f / l_i[m][r];
            size_t row = (size_t)bh * S_LEN + rowb0 + m * 64 + quad * 4 + r;
            float* orow = out + row * D_DIM;
            #pragma unroll
            for (int db = 0; db < 8; ++db)
                orow[db * 16 + ln] = o[m][db][r] * inv;
        }
    }
}

extern "C" void kernel_launch(void* const* d_in, const int* in_sizes, int n_in,
                              void* d_out, int out_size, void* d_ws, size_t ws_size,
                              hipStream_t stream) {
    const float* q = (const float*)d_in[0];
    const float* k = (const float*)d_in[1];
    const float* v = (const float*)d_in[2];
    float* out = (float*)d_out;
    const int bh = in_sizes[0] / (S_LEN * D_DIM);     // 32
    const size_t kelems = (size_t)bh * S_LEN * D_DIM; // 8.39M

    int tc = 0;
    for (int i = 0; i < NQT; ++i) tc += (2 * i + 2 + CHUNK - 1) / CHUNK;  // 40
    const size_t need_full = kelems * 2 * 3 + (size_t)bh * tc * SLOT * sizeof(float);

    if (ws_size >= need_full) {
        u16* qw = (u16*)d_ws;
        u16* kw = qw + kelems;
        u16* vt = kw + kelems;
        float* parts = (float*)(vt + kelems);
        conv_bf16<<<(int)(kelems / 1024), 256, 0, stream>>>(q, qw);
        conv_bf16<<<(int)(kelems / 1024), 256, 0, stream>>>(k, kw);
        trans_v<<<dim3((S_LEN / 64) * (D_DIM / 64), bh), 256, 0, stream>>>(v, vt);
        fa_chunk<<<dim3(tc, bh), 256, 0, stream>>>(qw, kw, vt, parts);
        fa_combine<<<dim3(NQT, bh), 256, 0, stream>>>(parts, out);
    } else {
        u16* kw = (u16*)d_ws;
        u16* vt = kw + kelems;
        conv_bf16<<<(int)(kelems / 1024), 256, 0, stream>>>(k, kw);
        trans_v<<<dim3((S_LEN / 64) * (D_DIM / 64), bh), 256, 0, stream>>>(v, vt);
        fa_mono<<<dim3(S_LEN / BM, bh), 256, 0, stream>>>(q, kw, vt, out);
    }
}

// Round 5
// 234.082 us; speedup vs baseline: 1.7928x; 1.7928x over previous
//
#include <hip/hip_runtime.h>

#define S_LEN 2048
#define D_DIM 128
#define BM 128
#define BN 64
#define NQT (S_LEN / BM)   // 16

typedef __attribute__((ext_vector_type(8))) short short8;
typedef __attribute__((ext_vector_type(4))) float floatx4;
typedef unsigned short u16;

__device__ __forceinline__ u16 f2b(float f) {
    union { float f; unsigned u; } x; x.f = f;
    unsigned r = x.u + 0x7FFFu + ((x.u >> 16) & 1u);  // RNE
    return (u16)(r >> 16);
}
__device__ __forceinline__ float b2f(u16 h) {
    union { unsigned u; float f; } x; x.u = ((unsigned)h) << 16;
    return x.f;
}
__device__ __forceinline__ void gld_lds16(const void* g, void* l) {
    __builtin_amdgcn_global_load_lds(
        (const __attribute__((address_space(1))) unsigned int*)g,
        (__attribute__((address_space(3))) unsigned int*)l, 16, 0, 0);
}
__device__ __forceinline__ floatx4 mfma16(short8 a, short8 b, floatx4 c) {
    return __builtin_amdgcn_mfma_f32_16x16x32_bf16(a, b, c, 0, 0, 0);
}

// ---------------- fused pre-pass: K fp32->bf16 (x<32) | V transpose (x>=32) ----
// V path: LDS fp32 tile 64s x 64d, row stride 65 dwords -> uniform 2-way banks
// on both phases (free per m136). Verified correct in r4 (absmax 0.0156).
__global__ __launch_bounds__(256) void prep_kv(const float* __restrict__ k,
                                               const float* __restrict__ v,
                                               u16* __restrict__ kw,
                                               u16* __restrict__ vt) {
    const int x   = blockIdx.x;
    const int bh  = blockIdx.y;
    const int tid = threadIdx.x;
    if (x < 32) {
        const float* src = k + (size_t)bh * S_LEN * D_DIM + (size_t)x * 8192;
        u16* dst = kw + (size_t)bh * S_LEN * D_DIM + (size_t)x * 8192;
        #pragma unroll
        for (int i = 0; i < 8; ++i) {
            int e = i * 1024 + tid * 4;
            float4 xx = *(const float4*)(src + e);
            ushort4 h;
            h.x = f2b(xx.x); h.y = f2b(xx.y); h.z = f2b(xx.z); h.w = f2b(xx.w);
            *(ushort4*)(dst + e) = h;
        }
    } else {
        __shared__ float T[64][65];
        const int t  = x - 32;           // 0..63
        const int s0 = (t >> 1) * 64;
        const int d0 = (t & 1) * 64;
        const float* vb = v + ((size_t)bh * S_LEN + s0) * D_DIM + d0;
        #pragma unroll
        for (int i = 0; i < 4; ++i) {
            int unit = i * 256 + tid;
            int s = unit >> 4;
            int c = (unit & 15) * 4;
            float4 xx = *(const float4*)(vb + s * D_DIM + c);
            T[s][c + 0] = xx.x; T[s][c + 1] = xx.y;
            T[s][c + 2] = xx.z; T[s][c + 3] = xx.w;
        }
        __syncthreads();
        u16* ob = vt + (size_t)bh * D_DIM * S_LEN + (size_t)d0 * S_LEN + s0;
        #pragma unroll
        for (int i = 0; i < 4; ++i) {
            int unit = i * 256 + tid;
            int d  = unit >> 4;
            int sl = (unit & 15) * 4;
            ushort4 h;
            h.x = f2b(T[sl + 0][d]); h.y = f2b(T[sl + 1][d]);
            h.z = f2b(T[sl + 2][d]); h.w = f2b(T[sl + 3][d]);
            *(ushort4*)(ob + (size_t)d * S_LEN + sl) = h;
        }
    }
}

// ---------------- monolithic flash kernel, load-balanced 1D grid ----------------
// block n<256: qt = 15-(n&15), bh = n>>4 ; n>=256: qt = n&15, bh = 16+((n-256)>>4)
// => blocks n and n+256 (which co-locate on a CU under round-robin XCD placement)
// have complementary qt: per-CU work = (2a+2)+(2(15-a)+2) = 34 tile-iters, uniform.
__global__ __launch_bounds__(256, 2) void fa_main(const float* __restrict__ q,
                                                  const u16* __restrict__ kw,
                                                  const u16* __restrict__ vtw,
                                                  float* __restrict__ out) {
    __shared__ u16 Ks[BN * D_DIM];   // XOR-swizzled granules
    __shared__ u16 Vt[D_DIM * BN];   // XOR-swizzled granules
    __shared__ u16 Ps[4][32][72];

    const int n  = blockIdx.x;
    const int hi = n >> 8;
    const int ii = n & 255;
    const int qt = hi ? (ii & 15) : 15 - (ii & 15);
    const int bh = hi * 16 + (ii >> 4);

    const int q0   = qt * BM;
    const int tid  = threadIdx.x;
    const int w    = tid >> 6;
    const int lane = tid & 63;
    const int ln   = lane & 15;
    const int quad = lane >> 4;
    constexpr float qs = 0.08838834764831845f * 1.44269504088896340f;
    const int rowb0 = q0 + w * 16;

    // ---- Q fragments (A-layout), scale*log2e folded ----
    short8 qf[2][4];
    #pragma unroll
    for (int m = 0; m < 2; ++m) {
        const float* qrow = q + ((size_t)bh * S_LEN + rowb0 + m * 64 + ln) * D_DIM;
        #pragma unroll
        for (int kc = 0; kc < 4; ++kc) {
            const float* p = qrow + kc * 32 + quad * 8;
            float4 x0 = *(const float4*)(p);
            float4 x1 = *(const float4*)(p + 4);
            short8 f;
            f[0] = (short)f2b(x0.x * qs); f[1] = (short)f2b(x0.y * qs);
            f[2] = (short)f2b(x0.z * qs); f[3] = (short)f2b(x0.w * qs);
            f[4] = (short)f2b(x1.x * qs); f[5] = (short)f2b(x1.y * qs);
            f[6] = (short)f2b(x1.z * qs); f[7] = (short)f2b(x1.w * qs);
            qf[m][kc] = f;
        }
    }
    floatx4 o[2][8];
    #pragma unroll
    for (int m = 0; m < 2; ++m)
        #pragma unroll
        for (int db = 0; db < 8; ++db) o[m][db] = (floatx4){0.f, 0.f, 0.f, 0.f};
    float m_i[2][4], l_i[2][4];
    #pragma unroll
    for (int m = 0; m < 2; ++m)
        #pragma unroll
        for (int r = 0; r < 4; ++r) { m_i[m][r] = -1e30f; l_i[m][r] = 0.f; }

    const u16* kb_bh = kw + (size_t)bh * S_LEN * D_DIM;
    const u16* vb_bh = vtw + (size_t)bh * D_DIM * S_LEN;

    const int NT = 2 * qt + 2;
    for (int t = 0; t < NT; ++t) {
        const int n0 = t * BN;
        {
            const u16* kb = kb_bh + (size_t)n0 * D_DIM;
            #pragma unroll
            for (int i = 0; i < 4; ++i) {
                int R0 = w * 16 + i * 4;
                int r = R0 + (lane >> 4);
                int p = lane & 15;
                gld_lds16(kb + r * D_DIM + ((p ^ (r & 7)) << 3), &Ks[R0 * D_DIM]);
            }
            #pragma unroll
            for (int i = 0; i < 4; ++i) {
                int D0 = (w * 4 + i) * 8;
                int d = D0 + (lane >> 3);
                int p = lane & 7;
                gld_lds16(vb_bh + (size_t)d * S_LEN + n0 + ((p ^ (d & 7)) << 3),
                          &Vt[D0 * BN]);
            }
        }
        __syncthreads();
        const bool skip0 = (n0 > rowb0 + 15);
        floatx4 sc[2][4];
        #pragma unroll
        for (int nb = 0; nb < 4; ++nb) {
            short8 kf[4];
            #pragma unroll
            for (int kc = 0; kc < 4; ++kc) {
                int r = nb * 16 + ln;
                kf[kc] = *(const short8*)&Ks[r * D_DIM + (((kc * 4 + quad) ^ (r & 7)) << 3)];
            }
            floatx4 a0 = (floatx4){0.f, 0.f, 0.f, 0.f};
            floatx4 a1 = (floatx4){0.f, 0.f, 0.f, 0.f};
            #pragma unroll
            for (int kc = 0; kc < 4; ++kc) {
                if (!skip0) a0 = mfma16(qf[0][kc], kf[kc], a0);
                a1 = mfma16(qf[1][kc], kf[kc], a1);
            }
            sc[0][nb] = a0; sc[1][nb] = a1;
        }
        #pragma unroll
        for (int m = 0; m < 2; ++m) {
            if (m == 0 && skip0) continue;
            const int rowb = rowb0 + m * 64;
            if (n0 + 63 > rowb) {
                #pragma unroll
                for (int nb = 0; nb < 4; ++nb) {
                    int colg = n0 + nb * 16 + ln;
                    #pragma unroll
                    for (int r = 0; r < 4; ++r)
                        if (colg > rowb + quad * 4 + r) sc[m][nb][r] = -1e30f;
                }
            }
            float mx[4];
            #pragma unroll
            for (int r = 0; r < 4; ++r)
                mx[r] = fmaxf(fmaxf(sc[m][0][r], sc[m][1][r]),
                              fmaxf(sc[m][2][r], sc[m][3][r]));
            #pragma unroll
            for (int off = 1; off < 16; off <<= 1) {
                #pragma unroll
                for (int r = 0; r < 4; ++r)
                    mx[r] = fmaxf(mx[r], __shfl_xor(mx[r], off));
            }
            float al[4], rs[4];
            #pragma unroll
            for (int r = 0; r < 4; ++r) {
                float mn = fmaxf(m_i[m][r], mx[r]);
                al[r] = __builtin_amdgcn_exp2f(m_i[m][r] - mn);
                m_i[m][r] = mn;
                rs[r] = 0.f;
            }
            #pragma unroll
            for (int nb = 0; nb < 4; ++nb) {
                #pragma unroll
                for (int r = 0; r < 4; ++r) {
                    float p = __builtin_amdgcn_exp2f(sc[m][nb][r] - m_i[m][r]);
                    u16 hb = f2b(p);
                    Ps[w][m * 16 + quad * 4 + r][nb * 16 + ln] = hb;
                    rs[r] += b2f(hb);
                }
            }
            #pragma unroll
            for (int off = 1; off < 16; off <<= 1) {
                #pragma unroll
                for (int r = 0; r < 4; ++r) rs[r] += __shfl_xor(rs[r], off);
            }
            #pragma unroll
            for (int r = 0; r < 4; ++r) l_i[m][r] = l_i[m][r] * al[r] + rs[r];
            #pragma unroll
            for (int db = 0; db < 8; ++db) {
                #pragma unroll
                for (int r = 0; r < 4; ++r) o[m][db][r] *= al[r];
            }
        }
        short8 pf[2][2];
        #pragma unroll
        for (int m = 0; m < 2; ++m) {
            if (m == 0 && skip0) continue;
            #pragma unroll
            for (int kc = 0; kc < 2; ++kc)
                pf[m][kc] = *(const short8*)&Ps[w][m * 16 + ln][kc * 32 + quad * 8];
        }
        #pragma unroll
        for (int db = 0; db < 8; ++db) {
            short8 vf[2];
            #pragma unroll
            for (int kc = 0; kc < 2; ++kc) {
                int d = db * 16 + ln;
                vf[kc] = *(const short8*)&Vt[d * BN + (((kc * 4 + quad) ^ (d & 7)) << 3)];
            }
            if (!skip0) {
                o[0][db] = mfma16(pf[0][0], vf[0], o[0][db]);
                o[0][db] = mfma16(pf[0][1], vf[1], o[0][db]);
            }
            o[1][db] = mfma16(pf[1][0], vf[0], o[1][db]);
            o[1][db] = mfma16(pf[1][1], vf[1], o[1][db]);
        }
        __syncthreads();
    }
    #pragma unroll
    for (int m = 0; m < 2; ++m) {
        #pragma unroll
        for (int r = 0; r < 4; ++r) {
            float inv = 1.f / l_i[m][r];
            size_t row = (size_t)bh * S_LEN + rowb0 + m * 64 + quad * 4 + r;
            float* orow = out + row * D_DIM;
            #pragma unroll
            for (int db = 0; db < 8; ++db)
                orow[db * 16 + ln] = o[m][db][r] * inv;
        }
    }
}

extern "C" void kernel_launch(void* const* d_in, const int* in_sizes, int n_in,
                              void* d_out, int out_size, void* d_ws, size_t ws_size,
                              hipStream_t stream) {
    const float* q = (const float*)d_in[0];
    const float* k = (const float*)d_in[1];
    const float* v = (const float*)d_in[2];
    float* out = (float*)d_out;
    const int bh = in_sizes[0] / (S_LEN * D_DIM);     // 32
    const size_t kelems = (size_t)bh * S_LEN * D_DIM; // 8.39M

    u16* kw = (u16*)d_ws;
    u16* vt = kw + kelems;
    prep_kv<<<dim3(96, bh), 256, 0, stream>>>(k, v, kw, vt);
    fa_main<<<dim3(NQT * bh), 256, 0, stream>>>(q, kw, vt, out);
}

// Round 6
// 217.801 us; speedup vs baseline: 1.9268x; 1.0748x over previous
//
#include <hip/hip_runtime.h>

#define S_LEN 2048
#define D_DIM 128
#define BM 128
#define BN 64
#define NQT (S_LEN / BM)   // 16

typedef __attribute__((ext_vector_type(8))) short short8;
typedef __attribute__((ext_vector_type(4))) float floatx4;
typedef __attribute__((ext_vector_type(4))) unsigned uintx4;
typedef unsigned short u16;

__device__ __forceinline__ u16 f2b(float f) {
    union { float f; unsigned u; } x; x.f = f;
    unsigned r = x.u + 0x7FFFu + ((x.u >> 16) & 1u);  // RNE
    return (u16)(r >> 16);
}
__device__ __forceinline__ float b2f(u16 h) {
    union { unsigned u; float f; } x; x.u = ((unsigned)h) << 16;
    return x.f;
}
__device__ __forceinline__ void gld_lds16(const void* g, void* l) {
    __builtin_amdgcn_global_load_lds(
        (const __attribute__((address_space(1))) unsigned int*)g,
        (__attribute__((address_space(3))) unsigned int*)l, 16, 0, 0);
}
__device__ __forceinline__ floatx4 mfma16(short8 a, short8 b, floatx4 c) {
    return __builtin_amdgcn_mfma_f32_16x16x32_bf16(a, b, c, 0, 0, 0);
}

// ---------------- fused pre-pass: K fp32->bf16 (x<32) | V transpose (x>=32) ----
// Verified correct in r4/r5 (absmax 0.0156). LDS fp32 tile 64x64 stride 65:
// uniform 2-way banks both phases (free per m136).
__global__ __launch_bounds__(256) void prep_kv(const float* __restrict__ k,
                                               const float* __restrict__ v,
                                               u16* __restrict__ kw,
                                               u16* __restrict__ vt) {
    const int x   = blockIdx.x;
    const int bh  = blockIdx.y;
    const int tid = threadIdx.x;
    if (x < 32) {
        const float* src = k + (size_t)bh * S_LEN * D_DIM + (size_t)x * 8192;
        u16* dst = kw + (size_t)bh * S_LEN * D_DIM + (size_t)x * 8192;
        #pragma unroll
        for (int i = 0; i < 8; ++i) {
            int e = i * 1024 + tid * 4;
            float4 xx = *(const float4*)(src + e);
            ushort4 h;
            h.x = f2b(xx.x); h.y = f2b(xx.y); h.z = f2b(xx.z); h.w = f2b(xx.w);
            *(ushort4*)(dst + e) = h;
        }
    } else {
        __shared__ float T[64][65];
        const int t  = x - 32;           // 0..63
        const int s0 = (t >> 1) * 64;
        const int d0 = (t & 1) * 64;
        const float* vb = v + ((size_t)bh * S_LEN + s0) * D_DIM + d0;
        #pragma unroll
        for (int i = 0; i < 4; ++i) {
            int unit = i * 256 + tid;
            int s = unit >> 4;
            int c = (unit & 15) * 4;
            float4 xx = *(const float4*)(vb + s * D_DIM + c);
            T[s][c + 0] = xx.x; T[s][c + 1] = xx.y;
            T[s][c + 2] = xx.z; T[s][c + 3] = xx.w;
        }
        __syncthreads();
        u16* ob = vt + (size_t)bh * D_DIM * S_LEN + (size_t)d0 * S_LEN + s0;
        #pragma unroll
        for (int i = 0; i < 4; ++i) {
            int unit = i * 256 + tid;
            int d  = unit >> 4;
            int sl = (unit & 15) * 4;
            ushort4 h;
            h.x = f2b(T[sl + 0][d]); h.y = f2b(T[sl + 1][d]);
            h.z = f2b(T[sl + 2][d]); h.w = f2b(T[sl + 3][d]);
            *(ushort4*)(ob + (size_t)d * S_LEN + sl) = h;
        }
    }
}

// ---------------- monolithic flash kernel, transposed-S, dbuf staging ----------
// S^T = K*Q^T (swap operands; qrow lives on ln). P^T built in registers via
// shfl-swap feeds PV as B-operand: O^T = V^T * P^T. No Ps LDS round-trip.
// One barrier/iter; next tile's global_load_lds issued right AFTER the barrier
// so its vmcnt drain at the NEXT barrier is hidden by the compute phase.
__global__ __launch_bounds__(256, 2) void fa_main(const float* __restrict__ q,
                                                  const u16* __restrict__ kw,
                                                  const u16* __restrict__ vtw,
                                                  float* __restrict__ out) {
    __shared__ u16 Ks[2][BN * D_DIM];   // XOR-swizzled granules
    __shared__ u16 Vt[2][D_DIM * BN];   // XOR-swizzled granules

    // complementary-pair balanced mapping (r5, verified): per-CU work uniform
    const int n  = blockIdx.x;
    const int hi = n >> 8;
    const int ii = n & 255;
    const int qt = hi ? (ii & 15) : 15 - (ii & 15);
    const int bh = hi * 16 + (ii >> 4);

    const int q0   = qt * BM;
    const int tid  = threadIdx.x;
    const int w    = tid >> 6;
    const int lane = tid & 63;
    const int ln   = lane & 15;
    const int quad = lane >> 4;
    constexpr float qs = 0.08838834764831845f * 1.44269504088896340f;
    const int rowb0 = q0 + w * 16;   // m-tile m rows: rowb0 + m*64 + ln

    // ---- Q fragments (B-operand; layout identical to A), scale*log2e folded ----
    short8 qf[2][4];
    #pragma unroll
    for (int m = 0; m < 2; ++m) {
        const float* qrow = q + ((size_t)bh * S_LEN + rowb0 + m * 64 + ln) * D_DIM;
        #pragma unroll
        for (int kc = 0; kc < 4; ++kc) {
            const float* p = qrow + kc * 32 + quad * 8;
            float4 x0 = *(const float4*)(p);
            float4 x1 = *(const float4*)(p + 4);
            short8 f;
            f[0] = (short)f2b(x0.x * qs); f[1] = (short)f2b(x0.y * qs);
            f[2] = (short)f2b(x0.z * qs); f[3] = (short)f2b(x0.w * qs);
            f[4] = (short)f2b(x1.x * qs); f[5] = (short)f2b(x1.y * qs);
            f[6] = (short)f2b(x1.z * qs); f[7] = (short)f2b(x1.w * qs);
            qf[m][kc] = f;
        }
    }

    floatx4 o[2][8];   // O^T accs: col=ln=qrow, row=quad*4+reg = d within db-block
    #pragma unroll
    for (int m = 0; m < 2; ++m)
        #pragma unroll
        for (int db = 0; db < 8; ++db) o[m][db] = (floatx4){0.f, 0.f, 0.f, 0.f};
    float m_i[2] = {-1e30f, -1e30f};
    float l_i[2] = {0.f, 0.f};

    const u16* kb_bh = kw + (size_t)bh * S_LEN * D_DIM;
    const u16* vb_bh = vtw + (size_t)bh * D_DIM * S_LEN;
    const int NT = 2 * qt + 2;

    auto stage = [&](int t, int b) {
        const int n0 = t * BN;
        const u16* kb = kb_bh + (size_t)n0 * D_DIM;
        #pragma unroll
        for (int i = 0; i < 4; ++i) {
            int R0 = w * 16 + i * 4;
            int r = R0 + (lane >> 4);
            int p = lane & 15;
            gld_lds16(kb + r * D_DIM + ((p ^ (r & 7)) << 3), &Ks[b][R0 * D_DIM]);
        }
        #pragma unroll
        for (int i = 0; i < 4; ++i) {
            int D0 = (w * 4 + i) * 8;
            int d = D0 + (lane >> 3);
            int p = lane & 7;
            gld_lds16(vb_bh + (size_t)d * S_LEN + n0 + ((p ^ (d & 7)) << 3),
                      &Vt[b][D0 * BN]);
        }
    };

    stage(0, 0);

    for (int t = 0; t < NT; ++t) {
        __syncthreads();                       // buf[t&1] staged (drain hidden)
        if (t + 1 < NT) stage(t + 1, (t + 1) & 1);   // prefetch next tile
        const u16* ks = Ks[t & 1];
        const u16* vs = Vt[t & 1];
        const int n0 = t * BN;
        const bool skip0 = (n0 > rowb0 + 15);  // m-tile0 fully masked (wave-uniform)

        // ---- S^T = K Q^T : col=ln=qrow, row=quad*4+reg = kv within nb-block ----
        floatx4 sc[2][4];
        #pragma unroll
        for (int nb = 0; nb < 4; ++nb) {
            short8 kf[4];
            #pragma unroll
            for (int kc = 0; kc < 4; ++kc) {
                int r = nb * 16 + ln;
                kf[kc] = *(const short8*)&ks[r * D_DIM + (((kc * 4 + quad) ^ (r & 7)) << 3)];
            }
            floatx4 a0 = (floatx4){0.f, 0.f, 0.f, 0.f};
            floatx4 a1 = (floatx4){0.f, 0.f, 0.f, 0.f};
            #pragma unroll
            for (int kc = 0; kc < 4; ++kc) {
                if (!skip0) a0 = mfma16(kf[kc], qf[0][kc], a0);
                a1 = mfma16(kf[kc], qf[1][kc], a1);
            }
            sc[0][nb] = a0; sc[1][nb] = a1;
        }

        // ---- per-m-tile: mask, online softmax (scalar state), B-frag build ----
        short8 bfr[2][2];
        const int s0l = ((quad & 1) << 5) + ln;   // src lane: quad 2*(q&1), same ln
        const int s1l = s0l + 16;                 // src lane: quad 2*(q&1)+1
        const bool hiq = (quad >> 1) != 0;
        #pragma unroll
        for (int m = 0; m < 2; ++m) {
            if (m == 0 && skip0) continue;
            const int rowb = rowb0 + m * 64;
            const int qrow = rowb + ln;
            if (n0 + 63 > rowb) {   // diagonal region: elementwise causal mask
                #pragma unroll
                for (int nb = 0; nb < 4; ++nb) {
                    int kvb = n0 + nb * 16 + quad * 4;
                    #pragma unroll
                    for (int r = 0; r < 4; ++r)
                        if (kvb + r > qrow) sc[m][nb][r] = -1e30f;
                }
            }
            // max over 16 in-lane + 2 shfls (quads hold disjoint kv)
            float mx = sc[m][0][0];
            #pragma unroll
            for (int nb = 0; nb < 4; ++nb)
                #pragma unroll
                for (int r = 0; r < 4; ++r) mx = fmaxf(mx, sc[m][nb][r]);
            mx = fmaxf(mx, __shfl_xor(mx, 16));
            mx = fmaxf(mx, __shfl_xor(mx, 32));
            float mn = fmaxf(m_i[m], mx);
            float al = __builtin_amdgcn_exp2f(m_i[m] - mn);
            m_i[m] = mn;
            float rs = 0.f;
            unsigned pk0[4], pk1[4];
            #pragma unroll
            for (int nb = 0; nb < 4; ++nb) {
                u16 h[4];
                #pragma unroll
                for (int r = 0; r < 4; ++r) {
                    float p = __builtin_amdgcn_exp2f(sc[m][nb][r] - mn);
                    h[r] = f2b(p);
                    rs += b2f(h[r]);   // rounded value: num/denom consistent
                }
                pk0[nb] = (unsigned)h[0] | ((unsigned)h[1] << 16);
                pk1[nb] = (unsigned)h[2] | ((unsigned)h[3] << 16);
            }
            rs += __shfl_xor(rs, 16);
            rs += __shfl_xor(rs, 32);
            l_i[m] = l_i[m] * al + rs;
            #pragma unroll
            for (int db = 0; db < 8; ++db) o[m][db] *= al;
            // B-frag (K=32) for kv-block p: lane(q,ln) needs kv=32p+8q+j.
            // src: nb=2p+(q>>1), src quads {2(q&1), 2(q&1)+1}.
            #pragma unroll
            for (int p = 0; p < 2; ++p) {
                unsigned l0 = __shfl((int)pk0[2 * p], s0l), h0 = __shfl((int)pk0[2 * p + 1], s0l);
                unsigned l1 = __shfl((int)pk1[2 * p], s0l), h1 = __shfl((int)pk1[2 * p + 1], s0l);
                unsigned l2 = __shfl((int)pk0[2 * p], s1l), h2 = __shfl((int)pk0[2 * p + 1], s1l);
                unsigned l3 = __shfl((int)pk1[2 * p], s1l), h3 = __shfl((int)pk1[2 * p + 1], s1l);
                union { uintx4 u; short8 s; } bc;
                bc.u = (uintx4){hiq ? h0 : l0, hiq ? h1 : l1, hiq ? h2 : l2, hiq ? h3 : l3};
                bfr[m][p] = bc.s;
            }
        }

        // ---- O^T += V^T P^T : A = Vt rows (b128, shared across m) ----
        #pragma unroll
        for (int db = 0; db < 8; ++db) {
            short8 vf[2];
            #pragma unroll
            for (int p = 0; p < 2; ++p) {
                int d = db * 16 + ln;
                vf[p] = *(const short8*)&vs[d * BN + (((p * 4 + quad) ^ (d & 7)) << 3)];
            }
            if (!skip0) {
                o[0][db] = mfma16(vf[0], bfr[0][0], o[0][db]);
                o[0][db] = mfma16(vf[1], bfr[0][1], o[0][db]);
            }
            o[1][db] = mfma16(vf[0], bfr[1][0], o[1][db]);
            o[1][db] = mfma16(vf[1], bfr[1][1], o[1][db]);
        }
    }

    // ---- epilogue: O = (O^T)^T / l ; lane ln owns qrow, regs are d ----
    #pragma unroll
    for (int m = 0; m < 2; ++m) {
        float inv = 1.f / l_i[m];
        size_t row = (size_t)bh * S_LEN + rowb0 + m * 64 + ln;
        float* orow = out + row * D_DIM + quad * 4;
        #pragma unroll
        for (int db = 0; db < 8; ++db) {
            float4 st = {o[m][db][0] * inv, o[m][db][1] * inv,
                         o[m][db][2] * inv, o[m][db][3] * inv};
            *(float4*)(orow + db * 16) = st;
        }
    }
}

extern "C" void kernel_launch(void* const* d_in, const int* in_sizes, int n_in,
                              void* d_out, int out_size, void* d_ws, size_t ws_size,
                              hipStream_t stream) {
    const float* q = (const float*)d_in[0];
    const float* k = (const float*)d_in[1];
    const float* v = (const float*)d_in[2];
    float* out = (float*)d_out;
    const int bh = in_sizes[0] / (S_LEN * D_DIM);     // 32
    const size_t kelems = (size_t)bh * S_LEN * D_DIM; // 8.39M

    u16* kw = (u16*)d_ws;
    u16* vt = kw + kelems;
    prep_kv<<<dim3(96, bh), 256, 0, stream>>>(k, v, kw, vt);
    fa_main<<<dim3(NQT * bh), 256, 0, stream>>>(q, kw, vt, out);
}